// Round 7
// baseline (173.567 us; speedup 1.0000x reference)
//
#include <hip/hip_runtime.h>

constexpr int N_NODES = 100000;
constexpr int D_FEAT  = 128;
constexpr int N_EDGES = 1600000;

constexpr int SHIFT    = 9;                                   // 512 nodes per bucket
constexpr int BUCKET_W = 1 << SHIFT;
constexpr int NB       = (N_NODES + BUCKET_W - 1) >> SHIFT;   // 196 buckets
static_assert(NB <= 256, "scan kernels assume NB <= 256");

constexpr int EPB       = 7680;                               // edges per multisplit block
constexpr int MS_BLOCKS = (N_EDGES + EPB - 1) / EPB;          // 209

constexpr int      SRC_BITS = 17;                             // 2^17 > 100000
constexpr unsigned SRC_MASK = (1u << SRC_BITS) - 1u;

constexpr int NTILE   = 8;                                    // feature tiles (16 feats = 64B line)
constexpr int TFEAT   = D_FEAT / NTILE;                       // 16
constexpr int NPB     = 128;                                  // nodes per gather block

typedef unsigned short ushort8 __attribute__((ext_vector_type(8)));
typedef float          floatx4 __attribute__((ext_vector_type(4)));

__device__ inline unsigned short f32_to_bf16_rne(float f)
{
    unsigned u = __float_as_uint(f);
    return (unsigned short)((u + 0x7FFFu + ((u >> 16) & 1u)) >> 16);
}
__device__ inline float bf16_to_f32(unsigned short h)
{
    return __uint_as_float((unsigned)h << 16);
}

// -------------------- scan helpers --------------------
__device__ inline int wave_incl_scan(int v)
{
    #pragma unroll
    for (int off = 1; off < 64; off <<= 1) {
        int t = __shfl_up(v, off);
        if ((threadIdx.x & 63) >= off) v += t;
    }
    return v;
}

__device__ inline int block_excl_scan_256(int v, int* wsum)
{
    int lane = threadIdx.x & 63, wid = threadIdx.x >> 6;
    int incl = wave_incl_scan(v);
    if (lane == 63) wsum[wid] = incl;
    __syncthreads();
    if (wid == 0) {
        int s = (lane < 4) ? wsum[lane] : 0;
        s = wave_incl_scan(s);
        if (lane < 4) wsum[lane] = s;
    }
    __syncthreads();
    int woff = (wid > 0) ? wsum[wid - 1] : 0;
    return incl + woff - v;
}

// -------------------- 1: per-block coarse histogram --------------------
__global__ void __launch_bounds__(256) coarse_hist_kernel(
    const int* __restrict__ dst, int* __restrict__ hist_blk)
{
    __shared__ int h[NB];
    const int tid = threadIdx.x, blk = blockIdx.x;
    for (int i = tid; i < NB; i += 256) h[i] = 0;
    __syncthreads();
    const int base = blk * EPB, cnt = min(EPB, N_EDGES - base);
    for (int k = tid; k < cnt; k += 256)
        atomicAdd(&h[dst[base + k] >> SHIFT], 1);
    __syncthreads();
    for (int b = tid; b < NB; b += 256)
        hist_blk[blk * NB + b] = h[b];
}

// -------------------- 2: single-block scan --------------------
__global__ void __launch_bounds__(256) scan_kernel(
    const int* __restrict__ hist_blk, int* __restrict__ gpre_blk,
    int* __restrict__ bucket_base, int* __restrict__ offsets)
{
    __shared__ int wsum[4];
    const int t = threadIdx.x;
    int run = 0;
    if (t < NB) {
        for (int k = 0; k < MS_BLOCKS; ++k) {
            gpre_blk[k * NB + t] = run;
            run += hist_blk[k * NB + t];
        }
    }
    int excl = block_excl_scan_256((t < NB) ? run : 0, wsum);
    if (t < NB)  bucket_base[t]  = excl;
    if (t == NB) bucket_base[NB] = excl;   // total = N_EDGES
    if (t == 0)  offsets[N_NODES] = N_EDGES;
}

// -------------------- 3: multisplit into NB buckets (u32 payload) --------------------
__global__ void __launch_bounds__(256) multisplit_kernel(
    const int* __restrict__ src, const int* __restrict__ dst,
    const int* __restrict__ hist_blk, const int* __restrict__ gpre_blk,
    const int* __restrict__ bucket_base, unsigned* __restrict__ coarse)
{
    __shared__ int lstart[NB], lcur[NB], gbase[NB];
    __shared__ int wsum[4];
    __shared__ unsigned pairs[EPB];

    const int t = threadIdx.x, blk = blockIdx.x;
    const int h = (t < NB) ? hist_blk[blk * NB + t] : 0;
    const int ls = block_excl_scan_256(h, wsum);
    if (t < NB) {
        lstart[t] = ls;
        lcur[t]   = ls;
        gbase[t]  = bucket_base[t] + gpre_blk[blk * NB + t];
    }
    __syncthreads();

    const int base = blk * EPB, cnt = min(EPB, N_EDGES - base);
    for (int k = t; k < cnt; k += 256) {
        int s = src[base + k];
        int d = dst[base + k];
        int b = d >> SHIFT;
        int slot = atomicAdd(&lcur[b], 1);
        pairs[slot] = ((unsigned)(d & (BUCKET_W - 1)) << SRC_BITS) | (unsigned)s;
    }
    __syncthreads();

    const int wid = t >> 6, lane = t & 63;
    for (int b = wid; b < NB; b += 4) {
        int st = lstart[b], c = lcur[b] - st;
        if (c == 0) continue;
        int gb = gbase[b];
        for (int i = lane; i < c; i += 64)
            coarse[gb + i] = pairs[st + i];
    }
}

// -------------------- 4: per-bucket sort; also emits offsets[] --------------------
__global__ void __launch_bounds__(256) bucket_sort_kernel(
    const unsigned* __restrict__ coarse, const int* __restrict__ bucket_base,
    int* __restrict__ offsets, int* __restrict__ sorted_src)
{
    __shared__ int hist[BUCKET_W], lcur[BUCKET_W];
    __shared__ int wsum[4];
    const int blk = blockIdx.x, t = threadIdx.x;
    const int node0  = blk << SHIFT;
    const int nn     = min(BUCKET_W, N_NODES - node0);
    const int segbeg = bucket_base[blk];
    const int segend = bucket_base[blk + 1];

    for (int j = t; j < BUCKET_W; j += 256) hist[j] = 0;
    __syncthreads();

    for (int i = segbeg + t; i < segend; i += 256)
        atomicAdd(&hist[coarse[i] >> SRC_BITS], 1);
    __syncthreads();

    const int a0 = hist[2 * t], a1 = hist[2 * t + 1];
    const int ex = block_excl_scan_256(a0 + a1, wsum);
    const int e0 = segbeg + ex, e1 = e0 + a0;
    if (2 * t     < nn) offsets[node0 + 2 * t]     = e0;
    if (2 * t + 1 < nn) offsets[node0 + 2 * t + 1] = e1;
    lcur[2 * t] = e0;
    lcur[2 * t + 1] = e1;
    __syncthreads();

    for (int i = segbeg + t; i < segend; i += 256) {
        unsigned p = coarse[i];
        int pos = atomicAdd(&lcur[p >> SRC_BITS], 1);
        sorted_src[pos] = (int)(p & SRC_MASK);
    }
}

// -------------------- 5: x (f32) -> xh_t (bf16, feature-tiled) --------------------
// xh_t[tile][node][16 feats]; tile = feat >> 4. One thread per (node, tile, half):
// reads 32 B of x (coalesced: 16 consecutive threads cover one node row),
// writes 16 B into the tile slice.
__global__ void __launch_bounds__(256) convert_tiled_kernel(
    const float* __restrict__ x, unsigned short* __restrict__ xh_t)
{
    const int unit = blockIdx.x * 256 + threadIdx.x;     // N_NODES*16 units
    if (unit >= N_NODES * NTILE * 2) return;
    const int half = unit & 1;
    const int tile = (unit >> 1) & 7;
    const int n    = unit >> 4;

    const float4* px = reinterpret_cast<const float4*>(
        x + (size_t)n * D_FEAT + tile * TFEAT + half * 8);
    float4 f0 = px[0];
    float4 f1 = px[1];
    ushort8 h;
    h[0] = f32_to_bf16_rne(f0.x); h[1] = f32_to_bf16_rne(f0.y);
    h[2] = f32_to_bf16_rne(f0.z); h[3] = f32_to_bf16_rne(f0.w);
    h[4] = f32_to_bf16_rne(f1.x); h[5] = f32_to_bf16_rne(f1.y);
    h[6] = f32_to_bf16_rne(f1.z); h[7] = f32_to_bf16_rne(f1.w);

    *reinterpret_cast<ushort8*>(
        xh_t + ((size_t)tile * N_NODES + n) * TFEAT + half * 8) = h;
}

// -------------------- 6: feature-tiled gather-accumulate --------------------
// blockIdx & 7 = tile -> XCD affinity (round-robin dispatch heuristic): each
// XCD's L2 holds one 3.2 MB tile slice. Thread pair (half 0/1) owns one node's
// 16-feature tile chunk; together they write one full 64-B out line.
__global__ void __launch_bounds__(256) gather_tiled_kernel(
    const unsigned short* __restrict__ xh_t, const int* __restrict__ offsets,
    const int* __restrict__ sorted_src, float* __restrict__ out)
{
    const int tile = blockIdx.x & 7;
    const int nb   = blockIdx.x >> 3;
    const int slot = threadIdx.x >> 1;
    const int half = threadIdx.x & 1;
    const int g    = nb * NPB + slot;
    if (g >= N_NODES) return;

    const int beg = offsets[g];
    const int end = offsets[g + 1];
    const unsigned short* xb = xh_t + (size_t)tile * N_NODES * TFEAT + half * 8;

    float acc[8] = {0.f, 0.f, 0.f, 0.f, 0.f, 0.f, 0.f, 0.f};

    int e = beg;
    for (; e + 4 <= end; e += 4) {
        ushort8 v[4];
        #pragma unroll
        for (int u = 0; u < 4; ++u) {
            int s = sorted_src[e + u];
            v[u] = *reinterpret_cast<const ushort8*>(xb + (size_t)s * TFEAT);
        }
        #pragma unroll
        for (int u = 0; u < 4; ++u) {
            #pragma unroll
            for (int j = 0; j < 8; ++j) acc[j] += bf16_to_f32(v[u][j]);
        }
    }
    for (; e < end; ++e) {
        int s = sorted_src[e];
        ushort8 v = *reinterpret_cast<const ushort8*>(xb + (size_t)s * TFEAT);
        #pragma unroll
        for (int j = 0; j < 8; ++j) acc[j] += bf16_to_f32(v[j]);
    }

    floatx4 a = {acc[0], acc[1], acc[2], acc[3]};
    floatx4 b = {acc[4], acc[5], acc[6], acc[7]};
    float* o = out + (size_t)g * D_FEAT + tile * TFEAT + half * 8;
    __builtin_nontemporal_store(a, reinterpret_cast<floatx4*>(o));
    __builtin_nontemporal_store(b, reinterpret_cast<floatx4*>(o + 4));
}

// -------------------- fallback: direct atomic scatter-add --------------------
__global__ void __launch_bounds__(256) atomic_scatter_kernel(
    const float* __restrict__ x, const int* __restrict__ src,
    const int* __restrict__ dst, float* __restrict__ out)
{
    long long T = (long long)blockIdx.x * blockDim.x + threadIdx.x;
    int edge = (int)(T >> 5), chunk = (int)(T & 31);
    if (edge >= N_EDGES) return;
    int s = src[edge], d = dst[edge];
    const float4 v = *reinterpret_cast<const float4*>(x + (long long)s * D_FEAT + chunk * 4);
    float* o = out + (long long)d * D_FEAT + chunk * 4;
    atomicAdd(o + 0, v.x); atomicAdd(o + 1, v.y);
    atomicAdd(o + 2, v.z); atomicAdd(o + 3, v.w);
}

// -------------------- launch --------------------
extern "C" void kernel_launch(void* const* d_in, const int* in_sizes, int n_in,
                              void* d_out, int out_size, void* d_ws, size_t ws_size,
                              hipStream_t stream)
{
    const float* x          = (const float*)d_in[0];
    const int*   edge_index = (const int*)d_in[1];
    const int*   src        = edge_index;
    const int*   dst        = edge_index + N_EDGES;
    float*       out        = (float*)d_out;

    // workspace layout (bytes). xh_t overlays {coarse, hist_blk, gpre_blk}:
    // all three are dead once bucket_sort finishes; convert runs after it.
    char*  ws       = (char*)d_ws;
    size_t o_off    = 0;                                        // offsets: N+1 ints
    size_t o_bb     = o_off + (size_t)(N_NODES + 2) * 4;        // bucket_base: NB+1
    size_t o_sorted = (o_bb + (size_t)(NB + 2) * 4 + 15) & ~(size_t)15;
    size_t o_union  = (o_sorted + (size_t)N_EDGES * 4 + 15) & ~(size_t)15;
    size_t o_coarse = o_union;
    size_t o_hblk   = o_coarse + (size_t)N_EDGES * 4;
    size_t o_gpre   = o_hblk + (size_t)MS_BLOCKS * NB * 4;
    size_t end_sort = o_gpre + (size_t)MS_BLOCKS * NB * 4;
    size_t o_xh     = o_union;
    size_t end_xh   = o_xh + (size_t)N_NODES * D_FEAT * 2;
    size_t need     = (end_sort > end_xh ? end_sort : end_xh);  // ~32.8 MB

    int*      offsets     = (int*)(ws + o_off);
    int*      bucket_base = (int*)(ws + o_bb);
    int*      sorted_src  = (int*)(ws + o_sorted);
    unsigned* coarse      = (unsigned*)(ws + o_coarse);
    int*      hist_blk    = (int*)(ws + o_hblk);
    int*      gpre_blk    = (int*)(ws + o_gpre);
    unsigned short* xh_t  = (unsigned short*)(ws + o_xh);

    const int block = 256;

    if (ws_size < need) {
        // fallback: correct-but-slow atomic path
        (void)hipMemsetAsync(out, 0, (size_t)N_NODES * D_FEAT * sizeof(float), stream);
        const long long tt = (long long)N_EDGES * 32;
        atomic_scatter_kernel<<<(int)((tt + block - 1) / block), block, 0, stream>>>(
            x, src, dst, out);
        return;
    }

    coarse_hist_kernel<<<MS_BLOCKS, block, 0, stream>>>(dst, hist_blk);
    scan_kernel<<<1, block, 0, stream>>>(hist_blk, gpre_blk, bucket_base, offsets);
    multisplit_kernel<<<MS_BLOCKS, block, 0, stream>>>(
        src, dst, hist_blk, gpre_blk, bucket_base, coarse);
    bucket_sort_kernel<<<NB, block, 0, stream>>>(
        coarse, bucket_base, offsets, sorted_src);

    const int cunits = N_NODES * NTILE * 2;
    convert_tiled_kernel<<<(cunits + block - 1) / block, block, 0, stream>>>(x, xh_t);

    const int nblk = (N_NODES + NPB - 1) / NPB;   // 782 node blocks
    gather_tiled_kernel<<<nblk * NTILE, block, 0, stream>>>(
        xh_t, offsets, sorted_src, out);
}